// Round 10
// baseline (257.469 us; speedup 1.0000x reference)
//
#include <hip/hip_runtime.h>
#include <hip/hip_bf16.h>
#include <stdint.h>

typedef __bf16 v8bf __attribute__((ext_vector_type(8)));
typedef short v4s __attribute__((ext_vector_type(4)));
typedef float f32x4 __attribute__((ext_vector_type(4)));
typedef float f32x2 __attribute__((ext_vector_type(2)));

__device__ __forceinline__ void gload_lds16(const void* g, void* l) {
    __builtin_amdgcn_global_load_lds(
        (const __attribute__((address_space(1))) void*)g,
        (__attribute__((address_space(3))) void*)l, 16, 0, 0);
}

__device__ __forceinline__ unsigned short f2bf(float f) {
    __hip_bfloat16 h = __float2bfloat16(f);
    return __builtin_bit_cast(unsigned short, h);
}

// zero e unless keep-bit (sign-extended to m) is set: e & m
__device__ __forceinline__ float andf(float e, int m) {
    return __builtin_bit_cast(float, __builtin_bit_cast(unsigned int, e) & (unsigned int)m);
}

// sign-extended single-bit extract: 1 VALU op (v_bfe_i32).
__device__ __forceinline__ int sbit(unsigned int w, int off) {
    int m;
    asm("v_bfe_i32 %0, %1, %2, 1" : "=v"(m) : "v"(w), "v"(off));
    return m;
}

// counted-vmcnt barriers (T4): raw s_barrier, loads stay in flight across it.
#define WAITV4_BAR() asm volatile("s_waitcnt vmcnt(4)\n\ts_barrier" ::: "memory")
#define WAITV0_BAR() asm volatile("s_waitcnt vmcnt(0)\n\ts_barrier" ::: "memory")
#define RAW_BAR() asm volatile("s_barrier" ::: "memory")

// K=16 bf16 MFMA: D = A*B + C. A,B = 4 bf16 (2 VGPRs).
// A layout: A[m=lane&15][k=(lane>>4)*4 + j]  == C/D layout of a prior MFMA.
__device__ __forceinline__ f32x4 mfma16x16x16bf(v4s a, v4s b, f32x4 c) {
#if __has_builtin(__builtin_amdgcn_mfma_f32_16x16x16bf16_1k)
    return __builtin_amdgcn_mfma_f32_16x16x16bf16_1k(a, b, c, 0, 0, 0);
#elif __has_builtin(__builtin_amdgcn_mfma_f32_16x16x16_bf16)
    return __builtin_amdgcn_mfma_f32_16x16x16_bf16(a, b, c, 0, 0, 0);
#else
    asm("s_nop 1\n\t"
        "v_mfma_f32_16x16x16_bf16 %0, %1, %2, %0\n\t"
        "s_nop 7\n\ts_nop 3"
        : "+v"(c) : "v"(a), "v"(b));
    return c;
#endif
}

// ---- fused conversion: xc = concat(x,c) bf16 [8][2048][512]; Wbf = 4 weights
__global__ __launch_bounds__(256) void cvt_xcw(const float* __restrict__ x,
                                               const float* __restrict__ c,
                                               const float* __restrict__ wq,
                                               const float* __restrict__ wk,
                                               const float* __restrict__ wv,
                                               const float* __restrict__ wp,
                                               __hip_bfloat16* __restrict__ xc,
                                               __hip_bfloat16* __restrict__ wout) {
    int bid = blockIdx.x;
    if (bid < 8192) {
        int i = bid * 256 + threadIdx.x;
        long e = (long)i * 4;
        int b = (int)(e >> 20);
        int rem = (int)(e & ((1 << 20) - 1));
        int r = rem >> 9;
        int col = rem & 511;
        const float* src = (r < 1024) ? (x + ((long)b << 19) + (long)r * 512 + col)
                                      : (c + ((long)b << 19) + (long)(r - 1024) * 512 + col);
        float4 v = *(const float4*)src;
        ushort4 o;
        o.x = f2bf(v.x); o.y = f2bf(v.y); o.z = f2bf(v.z); o.w = f2bf(v.w);
        ((ushort4*)xc)[i] = o;
    } else {
        int i = (bid - 8192) * 256 + threadIdx.x;
        int e = i * 4;
        int w = e >> 18;
        int off = e & ((1 << 18) - 1);
        const float* src = (w == 0 ? wq : w == 1 ? wk : w == 2 ? wv : wp) + off;
        float4 val = *(const float4*)src;
        ushort4 o;
        o.x = f2bf(val.x); o.y = f2bf(val.y); o.z = f2bf(val.z); o.w = f2bf(val.w);
        ((ushort4*)wout)[i] = o;
    }
}

// mask int32 [8][1024][2048] -> bit-packed KEEP-bits (inverted mask),
// TRANSPOSED uint64 [8][word 32][q 1024].
__global__ __launch_bounds__(256) void cvt_mask(const int* __restrict__ mask,
                                                unsigned long long* __restrict__ mbt) {
    int t = threadIdx.x;
    long base = (long)blockIdx.x * 1024;
#pragma unroll
    for (int j = 0; j < 4; j++) {
        long i = base + j * 256 + t;            // [b][q][key] linear
        int v = mask[i] == 0;                   // keep-bit
        unsigned long long bits = __ballot(v);
        if ((t & 63) == 0) {
            int b = (int)(i >> 21);
            int q = (int)((i >> 11) & 1023);
            int word = (int)((i >> 6) & 31);
            mbt[((long)b * 32 + word) * 1024 + q] = bits;
        }
    }
}

// ---- fused QKV projection GEMM ------------------------------------------
// C[m,n] = sum_k xc[m,k]*Wbf[n,k], M=16384, N=1536. y<4: Q (only x-rows,
// early-exit for c-row blocks), 4<=y<8: K, y>=8: V (2-pass LDS transpose).
// T4 counted-vmcnt main loop; coalesced Q/K epilogue via LDS T.
__global__ __launch_bounds__(256) void gemm_qkv(const __hip_bfloat16* __restrict__ A,
                                                const __hip_bfloat16* __restrict__ Bw,
                                                __hip_bfloat16* __restrict__ Qw,
                                                __hip_bfloat16* __restrict__ Kw,
                                                __hip_bfloat16* __restrict__ Vtw) {
    __shared__ union {
        struct { __hip_bfloat16 As[2][128 * 32]; __hip_bfloat16 Bs[2][128 * 32]; } s;
        __hip_bfloat16 T[64 * 138];   // 17.6 KB epilogue buffer (QK: stride 138; V: 136)
    } u;
    const int tid = threadIdx.x;
    const int wave = tid >> 6, lane = tid & 63;
    const int m0 = blockIdx.x * 128, n0 = blockIdx.y * 128;

    const bool isQ = (blockIdx.y < 4);
    const int rr_base = m0 & 2047;
    if (isQ && rr_base >= 1024) return;   // Q of c-rows: output discarded

    const int la = lane >> 2;
    const int kc = (lane & 3) * 8;
    const long ga0 = (long)(m0 + wave * 16 + la) * 512 + kc;
    const long ga1 = (long)(m0 + (wave + 4) * 16 + la) * 512 + kc;
    const long gb0 = (long)(n0 + wave * 16 + la) * 512 + kc;
    const long gb1 = (long)(n0 + (wave + 4) * 16 + la) * 512 + kc;

    f32x4 acc[4][4] = {};
    const int mw = (wave & 1) * 64, nw = (wave >> 1) * 64;
    const int lrow = lane & 15, lk = (lane >> 4) * 8;

    // prologue: stage k-tile 0 into buf 0 (4 DMA in flight)
    gload_lds16(A + ga0, &u.s.As[0][wave * 512]);
    gload_lds16(A + ga1, &u.s.As[0][(wave + 4) * 512]);
    gload_lds16(Bw + gb0, &u.s.Bs[0][wave * 512]);
    gload_lds16(Bw + gb1, &u.s.Bs[0][(wave + 4) * 512]);

    for (int it = 0; it < 16; ++it) {
        const int cur = it & 1;
        if (it < 15) {
            const int k0 = (it + 1) * 32;
            gload_lds16(A + ga0 + k0, &u.s.As[cur ^ 1][wave * 512]);
            gload_lds16(A + ga1 + k0, &u.s.As[cur ^ 1][(wave + 4) * 512]);
            gload_lds16(Bw + gb0 + k0, &u.s.Bs[cur ^ 1][wave * 512]);
            gload_lds16(Bw + gb1 + k0, &u.s.Bs[cur ^ 1][(wave + 4) * 512]);
            WAITV4_BAR();   // tile `it` landed for all waves; tile it+1 flies
        } else {
            WAITV0_BAR();
        }
        v8bf a[4], b[4];
#pragma unroll
        for (int i = 0; i < 4; i++) {
            a[i] = *(const v8bf*)&u.s.As[cur][(mw + i * 16 + lrow) * 32 + lk];
            b[i] = *(const v8bf*)&u.s.Bs[cur][(nw + i * 16 + lrow) * 32 + lk];
        }
        __builtin_amdgcn_s_setprio(1);
#pragma unroll
        for (int mi = 0; mi < 4; mi++)
#pragma unroll
            for (int ni = 0; ni < 4; ni++)
                acc[mi][ni] = __builtin_amdgcn_mfma_f32_16x16x32_bf16(a[mi], b[ni], acc[mi][ni], 0, 0, 0);
        __builtin_amdgcn_s_setprio(0);
        RAW_BAR();   // all waves done reading buf[cur]; next DMA may overwrite
    }

    const int lq = lane >> 4;
    const int b_ = m0 >> 11;
    if (blockIdx.y < 8) {
        // ---- coalesced Q/K epilogue via T[64][138], 2 passes of 64 rows ----
        const float qs = isQ ? 0.1803368801f : 1.f;   // 0.125*log2(e) folded into Q
#pragma unroll
        for (int pass = 0; pass < 2; ++pass) {
            if (pass) __syncthreads();             // protect T reuse
            if ((wave & 1) == pass) {              // waves owning mw = pass*64
#pragma unroll
                for (int mi = 0; mi < 4; mi++)
#pragma unroll
                    for (int ni = 0; ni < 4; ni++) {
                        const int nl = nw + ni * 16 + lrow;
#pragma unroll
                        for (int r = 0; r < 4; r++)
                            u.T[(mi * 16 + lq * 4 + r) * 138 + nl] =
                                __float2bfloat16(acc[mi][ni][r] * qs);
                    }
            }
            __syncthreads();
#pragma unroll
            for (int i = 0; i < 4; i++) {
                int sI = tid + i * 256;            // 0..1023: 64 rows x 16 chunks
                int row = sI >> 4, ch = sI & 15;
                int grow = m0 + pass * 64 + row;
                int rr = grow & 2047;
                int gcol = n0 + ch * 8;
                int h = (gcol & 511) >> 6, dh = gcol & 63;
                uint4 v = *(const uint4*)&u.T[row * 138 + ch * 8];
                if (isQ)
                    *(uint4*)&Qw[((long)(b_ * 8 + h) * 1024 + rr) * 64 + dh] = v;
                else
                    *(uint4*)&Kw[((long)(b_ * 8 + h) * 2048 + rr) * 64 + dh] = v;
            }
        }
    } else {
        const int no = (blockIdx.y - 8) * 128;
        const int rrb = m0 & 2047;
#pragma unroll
        for (int pass = 0; pass < 2; ++pass) {
            __syncthreads();
            if ((wave >> 1) == pass) {
#pragma unroll
                for (int mi = 0; mi < 4; mi++)
#pragma unroll
                    for (int ni = 0; ni < 4; ni++) {
                        int n_l = ni * 16 + lrow;          // 0..63 within pass
                        int m_l = mw + mi * 16 + lq * 4;
                        ushort4 pk;
                        pk.x = f2bf(acc[mi][ni][0]); pk.y = f2bf(acc[mi][ni][1]);
                        pk.z = f2bf(acc[mi][ni][2]); pk.w = f2bf(acc[mi][ni][3]);
                        *(ushort4*)&u.T[n_l * 136 + m_l] = pk;
                    }
            }
            __syncthreads();
#pragma unroll
            for (int i = 0; i < 4; i++) {
                int sI = tid + i * 256;                    // 0..1023
                int n_l = sI >> 4, ch = sI & 15;           // 64 rows x 16 chunks
                int ng = no + pass * 64 + n_l;
                int h = ng >> 6, dh = ng & 63;
                uint4 v = *(const uint4*)&u.T[n_l * 136 + ch * 8];
                *(uint4*)&Vtw[((long)(b_ * 8 + h) * 64 + dh) * 2048 + rrb + ch * 8] = v;
            }
        }
    }
}

// ---- output projection GEMM: d_out[m,n] = sum_k Yb[m,k]*Wp[n,k], fp32 out
// v3: counted-vmcnt pipeline (T4).
__global__ __launch_bounds__(256) void gemm_out(const __hip_bfloat16* __restrict__ A,
                                                const __hip_bfloat16* __restrict__ Bw,
                                                float* __restrict__ outp) {
    __shared__ __hip_bfloat16 As[2][128 * 32];
    __shared__ __hip_bfloat16 Bs[2][128 * 32];
    const int tid = threadIdx.x;
    const int wave = tid >> 6, lane = tid & 63;
    const int m0 = blockIdx.x * 128, n0 = blockIdx.y * 128;

    const int la = lane >> 2;
    const int kc = (lane & 3) * 8;
    const long ga0 = (long)(m0 + wave * 16 + la) * 512 + kc;
    const long ga1 = (long)(m0 + (wave + 4) * 16 + la) * 512 + kc;
    const long gb0 = (long)(n0 + wave * 16 + la) * 512 + kc;
    const long gb1 = (long)(n0 + (wave + 4) * 16 + la) * 512 + kc;

    f32x4 acc[4][4] = {};
    const int mw = (wave & 1) * 64, nw = (wave >> 1) * 64;
    const int lrow = lane & 15, lk = (lane >> 4) * 8;

    gload_lds16(A + ga0, &As[0][wave * 512]);
    gload_lds16(A + ga1, &As[0][(wave + 4) * 512]);
    gload_lds16(Bw + gb0, &Bs[0][wave * 512]);
    gload_lds16(Bw + gb1, &Bs[0][(wave + 4) * 512]);

    for (int it = 0; it < 16; ++it) {
        const int cur = it & 1;
        if (it < 15) {
            const int k0 = (it + 1) * 32;
            gload_lds16(A + ga0 + k0, &As[cur ^ 1][wave * 512]);
            gload_lds16(A + ga1 + k0, &As[cur ^ 1][(wave + 4) * 512]);
            gload_lds16(Bw + gb0 + k0, &Bs[cur ^ 1][wave * 512]);
            gload_lds16(Bw + gb1 + k0, &Bs[cur ^ 1][(wave + 4) * 512]);
            WAITV4_BAR();
        } else {
            WAITV0_BAR();
        }
        v8bf a[4], b[4];
#pragma unroll
        for (int i = 0; i < 4; i++) {
            a[i] = *(const v8bf*)&As[cur][(mw + i * 16 + lrow) * 32 + lk];
            b[i] = *(const v8bf*)&Bs[cur][(nw + i * 16 + lrow) * 32 + lk];
        }
        __builtin_amdgcn_s_setprio(1);
#pragma unroll
        for (int mi = 0; mi < 4; mi++)
#pragma unroll
            for (int ni = 0; ni < 4; ni++)
                acc[mi][ni] = __builtin_amdgcn_mfma_f32_16x16x32_bf16(a[mi], b[ni], acc[mi][ni], 0, 0, 0);
        __builtin_amdgcn_s_setprio(0);
        RAW_BAR();
    }

    const int lq = lane >> 4;
#pragma unroll
    for (int mi = 0; mi < 4; mi++)
#pragma unroll
        for (int ni = 0; ni < 4; ni++)
#pragma unroll
            for (int r = 0; r < 4; r++) {
                int grow = m0 + mw + mi * 16 + lq * 4 + r;
                int gcol = n0 + nw + ni * 16 + lrow;
                outp[(long)grow * 512 + gcol] = acc[mi][ni][r];
            }
}

// ---- flash attention v16: pair-permuted V, uint4-pattern extraction ------
// grid 512 (b=L&7 XCD-pinned, qt2=(L>>3)&7, h=L>>6). 8 waves, 128 q rows,
// shared staging (1 K-uint4 + 2 V-uint2 per thread per tile).
// V^T LDS is KEY-PERMUTED: pos(key) = 32*(nt>>1) + 8*lq + 4*(nt&1) + j for
// key = nt*16+lq*4+j — so subtile pair (2g,2g+1) fragments are the lo/hi
// 8B halves of ONE 16B chunk: PV = 8 ds_read_b128/tile vs 16 ds_read_b64.
// (Layout verified by write/read/numeric trace; v15's failure attributed to
// per-element __bf16 extraction — replaced with the known-good uint2
// bit_cast pattern used for P-packing since v9.) Carried-cur dbuf loop,
// ONE __syncthreads per tile, v13 softmax (keep-bits, v_bfe_i32, pk_add).
__global__ __launch_bounds__(512) void flash(const __hip_bfloat16* __restrict__ Q,
                                             const __hip_bfloat16* __restrict__ K,
                                             const __hip_bfloat16* __restrict__ Vt,
                                             const unsigned long long* __restrict__ Mbt,
                                             __hip_bfloat16* __restrict__ Y) {
    constexpr int LDT = 72;
    __shared__ __hip_bfloat16 Ks[2][64 * LDT];    // [buf][key][d]
    __shared__ __hip_bfloat16 Vts[2][64 * LDT];   // [buf][d][key-permuted]

    const int L = blockIdx.x;
    const int b = L & 7, qt2 = (L >> 3) & 7, h = L >> 6;
    const int bh = b * 8 + h;
    const int tid = threadIdx.x, w = tid >> 6, lane = tid & 63;
    const int lcol = lane & 15, lq = lane >> 4;
    const int qrow = qt2 * 128 + w * 16;          // wave's q-row base

    const __hip_bfloat16* Qp = Q + ((long)bh * 1024 + qrow + lcol) * 64 + lq * 8;
    const __hip_bfloat16* Kg = K + (long)bh * 2048 * 64;
    const __hip_bfloat16* Vg = Vt + (long)bh * 64 * 2048;
    const unsigned long long* Mp = Mbt + (long)b * 32 * 1024 + qrow + lcol;

    // staging geometry: K = 1 uint4/thread; V = 2 uint2/thread (permuted).
    // chunk p0 of row r0 holds keys [K6a..K6a+3] ++ [K6a+16..K6a+19].
    const int r0 = tid >> 3, p0 = tid & 7;        // row 0..63, 16B chunk 0..7
    const int K6a = (p0 >> 2) * 32 + (p0 & 3) * 4;
    const __hip_bfloat16* Vpa = Vg + (long)r0 * 2048 + K6a;
    const __hip_bfloat16* Vpb = Vpa + 16;

    // per-lane mask-bit offsets (within 32-bit half): bit = (nt&1)*16+lq*4+j
    int boff[8];
#pragma unroll
    for (int jj = 0; jj < 8; jj++)
        boff[jj] = (jj >> 2) * 16 + lq * 4 + (jj & 3);

    // Q B-frags (wave's 16 q rows), pre-scaled by 0.125*log2e
    v8bf bq0 = *(const v8bf*)(Qp);
    v8bf bq1 = *(const v8bf*)(Qp + 32);

    f32x4 O[4] = {};
    f32x2 ls = {0.f, 0.f};

    // prologue: stage tile 0 into buf 0; preload keep word 0
    unsigned long long mword = Mp[0];
    {
        uint4 k0 = ((const uint4*)Kg)[tid];
        uint2 va = *(const uint2*)(Vpa);
        uint2 vb = *(const uint2*)(Vpb);
        *(uint4*)&Ks[0][r0 * LDT + p0 * 8] = k0;
        uint4 vw; vw.x = va.x; vw.y = va.y; vw.z = vb.x; vw.w = vb.y;
        *(uint4*)&Vts[0][r0 * LDT + p0 * 8] = vw;
    }
    __syncthreads();

    int cur = 0;
    for (int kt = 0; kt < 32; kt++) {
        // keep-bits, split into 32-bit halves (already inverted by cvt_mask)
        const unsigned int kw_lo = (unsigned int)mword;
        const unsigned int kw_hi = (unsigned int)(mword >> 32);

        // issue next tile's global loads NOW; latency hides under compute
        uint4 nk0; uint2 nva, nvb;
        if (kt < 31) {
            nk0 = ((const uint4*)(Kg + ((kt + 1) << 12)))[tid];
            nva = *(const uint2*)(Vpa + (kt + 1) * 64);
            nvb = *(const uint2*)(Vpb + (kt + 1) * 64);
            mword = Mp[(long)(kt + 1) * 1024];
        }

        const __hip_bfloat16* Kb = Ks[cur];
        const __hip_bfloat16* Vb = Vts[cur];
#pragma unroll
        for (int g = 0; g < 2; g++) {
            const unsigned int kw = g ? kw_hi : kw_lo;
            // subtiles A = 2g, B = 2g+1: S^T = K rows x Q
            v8bf akA0 = *(const v8bf*)&Kb[((2 * g) * 16 + lcol) * LDT + lq * 8];
            v8bf akA1 = *(const v8bf*)&Kb[((2 * g) * 16 + lcol) * LDT + 32 + lq * 8];
            v8bf akB0 = *(const v8bf*)&Kb[((2 * g + 1) * 16 + lcol) * LDT + lq * 8];
            v8bf akB1 = *(const v8bf*)&Kb[((2 * g + 1) * 16 + lcol) * LDT + 32 + lq * 8];
            f32x4 stA = {}, stB = {};
            __builtin_amdgcn_s_setprio(1);
            stA = __builtin_amdgcn_mfma_f32_16x16x32_bf16(akA0, bq0, stA, 0, 0, 0);
            stA = __builtin_amdgcn_mfma_f32_16x16x32_bf16(akA1, bq1, stA, 0, 0, 0);
            stB = __builtin_amdgcn_mfma_f32_16x16x32_bf16(akB0, bq0, stB, 0, 0, 0);
            stB = __builtin_amdgcn_mfma_f32_16x16x32_bf16(akB1, bq1, stB, 0, 0, 0);
            __builtin_amdgcn_s_setprio(0);
            // masked exp2 (keep-bit sign-extend AND), both subtiles
            float eA0 = andf(__builtin_amdgcn_exp2f(stA[0]), sbit(kw, boff[0]));
            float eA1 = andf(__builtin_amdgcn_exp2f(stA[1]), sbit(kw, boff[1]));
            float eA2 = andf(__builtin_amdgcn_exp2f(stA[2]), sbit(kw, boff[2]));
            float eA3 = andf(__builtin_amdgcn_exp2f(stA[3]), sbit(kw, boff[3]));
            float eB0 = andf(__builtin_amdgcn_exp2f(stB[0]), sbit(kw, boff[4]));
            float eB1 = andf(__builtin_amdgcn_exp2f(stB[1]), sbit(kw, boff[5]));
            float eB2 = andf(__builtin_amdgcn_exp2f(stB[2]), sbit(kw, boff[6]));
            float eB3 = andf(__builtin_amdgcn_exp2f(stB[3]), sbit(kw, boff[7]));
            ls += (f32x2){eA0, eA1} + (f32x2){eA2, eA3};
            ls += (f32x2){eB0, eB1} + (f32x2){eB2, eB3};
            // pack P A-frags (K=16 layout: elem j = key 16*nt+lq*4+j)
            __hip_bfloat162 loA = __float22bfloat162_rn(make_float2(eA0, eA1));
            __hip_bfloat162 hiA = __float22bfloat162_rn(make_float2(eA2, eA3));
            __hip_bfloat162 loB = __float22bfloat162_rn(make_float2(eB0, eB1));
            __hip_bfloat162 hiB = __float22bfloat162_rn(make_float2(eB2, eB3));
            uint2 pkA, pkB;
            __builtin_memcpy(&pkA.x, &loA, 4);
            __builtin_memcpy(&pkA.y, &hiA, 4);
            __builtin_memcpy(&pkB.x, &loB, 4);
            __builtin_memcpy(&pkB.y, &hiB, 4);
            v4s paA = __builtin_bit_cast(v4s, pkA);
            v4s paB = __builtin_bit_cast(v4s, pkB);
            // PV: ONE b128 read per nd serves both subtiles (lo=A, hi=B);
            // halves split via the known-good uint2 bit_cast pattern.
            uint4 pw[4];
#pragma unroll
            for (int nd = 0; nd < 4; nd++)
                pw[nd] = *(const uint4*)&Vb[(nd * 16 + lcol) * LDT + g * 32 + lq * 8];
            __builtin_amdgcn_s_setprio(1);
#pragma unroll
            for (int nd = 0; nd < 4; nd++) {
                uint2 lo2; lo2.x = pw[nd].x; lo2.y = pw[nd].y;
                O[nd] = mfma16x16x16bf(paA, __builtin_bit_cast(v4s, lo2), O[nd]);
            }
#pragma unroll
            for (int nd = 0; nd < 4; nd++) {
                uint2 hi2; hi2.x = pw[nd].z; hi2.y = pw[nd].w;
                O[nd] = mfma16x16x16bf(paB, __builtin_bit_cast(v4s, hi2), O[nd]);
            }
            __builtin_amdgcn_s_setprio(0);
        }

        // write next tile into the other buffer; all waves finished reading
        // it before the previous barrier
        if (kt < 31) {
            *(uint4*)&Ks[cur ^ 1][r0 * LDT + p0 * 8] = nk0;
            uint4 vw; vw.x = nva.x; vw.y = nva.y; vw.z = nvb.x; vw.w = nvb.y;
            *(uint4*)&Vts[cur ^ 1][r0 * LDT + p0 * 8] = vw;
        }
        __syncthreads();
        cur ^= 1;
    }

    // row-sum: reduce over lq groups (lanes sharing lcol)
    float s = ls[0] + ls[1];
    s += __shfl_xor(s, 16);
    s += __shfl_xor(s, 32);
    // O C-layout rows are q = lq*4 + r; fetch matching 1/sum via shuffle
    float inv[4];
#pragma unroll
    for (int r = 0; r < 4; r++) inv[r] = 1.f / __shfl(s, lq * 4 + r);

    __hip_bfloat16* Yp = Y + ((long)b * 1024 + qrow) * 512 + h * 64 + lcol;
#pragma unroll
    for (int nd = 0; nd < 4; nd++)
#pragma unroll
        for (int r = 0; r < 4; r++)
            Yp[(long)(lq * 4 + r) * 512 + nd * 16] = __float2bfloat16(O[nd][r] * inv[r]);
}

// ---- launch -------------------------------------------------------------
extern "C" void kernel_launch(void* const* d_in, const int* in_sizes, int n_in,
                              void* d_out, int out_size, void* d_ws, size_t ws_size,
                              hipStream_t stream) {
    const float* x = (const float*)d_in[0];
    const float* c = (const float*)d_in[1];
    const int* mask = (const int*)d_in[2];
    const float* Wq = (const float*)d_in[3];
    const float* Wk = (const float*)d_in[4];
    const float* Wv = (const float*)d_in[5];
    const float* Wp = (const float*)d_in[6];

    char* ws = (char*)d_ws;
    __hip_bfloat16* xc  = (__hip_bfloat16*)(ws);                 // 16 MB (dead after gemm_qkv)
    __hip_bfloat16* Wbf = (__hip_bfloat16*)(ws + 16777216);      //  2 MB
    __hip_bfloat16* Qw  = (__hip_bfloat16*)(ws + 18874368);      //  8 MB
    __hip_bfloat16* Kw  = (__hip_bfloat16*)(ws + 27262976);      // 16 MB
    __hip_bfloat16* Vtw = (__hip_bfloat16*)(ws + 44040192);      // 16 MB
    __hip_bfloat16* Yb  = (__hip_bfloat16*)(ws + 60817408);      //  8 MB
    unsigned long long* Mbp = (unsigned long long*)(ws);         //  2 MB, aliases dead xc

    cvt_xcw<<<9216, 256, 0, stream>>>(x, c, Wq, Wk, Wv, Wp, xc, Wbf);
    gemm_qkv<<<dim3(128, 12), 256, 0, stream>>>(xc, Wbf, Qw, Kw, Vtw);
    cvt_mask<<<16384, 256, 0, stream>>>(mask, Mbp);   // after gemm_qkv: overwrites xc
    flash<<<512, 512, 0, stream>>>(Qw, Kw, Vtw, Mbp, Yb);
    gemm_out<<<dim3(64, 4), 256, 0, stream>>>(Yb, Wbf + 3 * 262144, (float*)d_out);
}

// Round 11
// 256.153 us; speedup vs baseline: 1.0051x; 1.0051x over previous
//
#include <hip/hip_runtime.h>
#include <hip/hip_bf16.h>
#include <stdint.h>

typedef __bf16 v8bf __attribute__((ext_vector_type(8)));
typedef short v4s __attribute__((ext_vector_type(4)));
typedef float f32x4 __attribute__((ext_vector_type(4)));
typedef float f32x2 __attribute__((ext_vector_type(2)));

__device__ __forceinline__ void gload_lds16(const void* g, void* l) {
    __builtin_amdgcn_global_load_lds(
        (const __attribute__((address_space(1))) void*)g,
        (__attribute__((address_space(3))) void*)l, 16, 0, 0);
}

__device__ __forceinline__ unsigned short f2bf(float f) {
    __hip_bfloat16 h = __float2bfloat16(f);
    return __builtin_bit_cast(unsigned short, h);
}

// zero e unless keep-bit (sign-extended to m) is set: e & m
__device__ __forceinline__ float andf(float e, int m) {
    return __builtin_bit_cast(float, __builtin_bit_cast(unsigned int, e) & (unsigned int)m);
}

// sign-extended single-bit extract: 1 VALU op (v_bfe_i32).
__device__ __forceinline__ int sbit(unsigned int w, int off) {
    int m;
    asm("v_bfe_i32 %0, %1, %2, 1" : "=v"(m) : "v"(w), "v"(off));
    return m;
}

// counted-vmcnt barriers (T4): raw s_barrier, loads stay in flight across it.
#define WAITV4_BAR() asm volatile("s_waitcnt vmcnt(4)\n\ts_barrier" ::: "memory")
#define WAITV3_BAR() asm volatile("s_waitcnt vmcnt(3)\n\ts_barrier" ::: "memory")
#define WAITV0_BAR() asm volatile("s_waitcnt vmcnt(0)\n\ts_barrier" ::: "memory")
#define RAW_BAR() asm volatile("s_barrier" ::: "memory")

// K=16 bf16 MFMA: D = A*B + C. A,B = 4 bf16 (2 VGPRs).
// A layout: A[m=lane&15][k=(lane>>4)*4 + j]  == C/D layout of a prior MFMA.
__device__ __forceinline__ f32x4 mfma16x16x16bf(v4s a, v4s b, f32x4 c) {
#if __has_builtin(__builtin_amdgcn_mfma_f32_16x16x16bf16_1k)
    return __builtin_amdgcn_mfma_f32_16x16x16bf16_1k(a, b, c, 0, 0, 0);
#elif __has_builtin(__builtin_amdgcn_mfma_f32_16x16x16_bf16)
    return __builtin_amdgcn_mfma_f32_16x16x16_bf16(a, b, c, 0, 0, 0);
#else
    asm("s_nop 1\n\t"
        "v_mfma_f32_16x16x16_bf16 %0, %1, %2, %0\n\t"
        "s_nop 7\n\ts_nop 3"
        : "+v"(c) : "v"(a), "v"(b));
    return c;
#endif
}

// ---- fused conversion: xc = concat(x,c) bf16 [8][2048][512]; Wbf = 4 weights
__global__ __launch_bounds__(256) void cvt_xcw(const float* __restrict__ x,
                                               const float* __restrict__ c,
                                               const float* __restrict__ wq,
                                               const float* __restrict__ wk,
                                               const float* __restrict__ wv,
                                               const float* __restrict__ wp,
                                               __hip_bfloat16* __restrict__ xc,
                                               __hip_bfloat16* __restrict__ wout) {
    int bid = blockIdx.x;
    if (bid < 8192) {
        int i = bid * 256 + threadIdx.x;
        long e = (long)i * 4;
        int b = (int)(e >> 20);
        int rem = (int)(e & ((1 << 20) - 1));
        int r = rem >> 9;
        int col = rem & 511;
        const float* src = (r < 1024) ? (x + ((long)b << 19) + (long)r * 512 + col)
                                      : (c + ((long)b << 19) + (long)(r - 1024) * 512 + col);
        float4 v = *(const float4*)src;
        ushort4 o;
        o.x = f2bf(v.x); o.y = f2bf(v.y); o.z = f2bf(v.z); o.w = f2bf(v.w);
        ((ushort4*)xc)[i] = o;
    } else {
        int i = (bid - 8192) * 256 + threadIdx.x;
        int e = i * 4;
        int w = e >> 18;
        int off = e & ((1 << 18) - 1);
        const float* src = (w == 0 ? wq : w == 1 ? wk : w == 2 ? wv : wp) + off;
        float4 val = *(const float4*)src;
        ushort4 o;
        o.x = f2bf(val.x); o.y = f2bf(val.y); o.z = f2bf(val.z); o.w = f2bf(val.w);
        ((ushort4*)wout)[i] = o;
    }
}

// mask int32 [8][1024][2048] -> bit-packed KEEP-bits (inverted mask),
// TRANSPOSED uint64 [8][word 32][q 1024].
__global__ __launch_bounds__(256) void cvt_mask(const int* __restrict__ mask,
                                                unsigned long long* __restrict__ mbt) {
    int t = threadIdx.x;
    long base = (long)blockIdx.x * 1024;
#pragma unroll
    for (int j = 0; j < 4; j++) {
        long i = base + j * 256 + t;            // [b][q][key] linear
        int v = mask[i] == 0;                   // keep-bit
        unsigned long long bits = __ballot(v);
        if ((t & 63) == 0) {
            int b = (int)(i >> 21);
            int q = (int)((i >> 11) & 1023);
            int word = (int)((i >> 6) & 31);
            mbt[((long)b * 32 + word) * 1024 + q] = bits;
        }
    }
}

// ---- fused QKV projection GEMM v5: 256x128 tile, 8 waves -----------------
// C[m,n] = sum_k xc[m,k]*Wbf[n,k], M=16384, N=1536. grid (64, 12):
// y<4: Q (early-exit for c-row blocks), 4<=y<8: K, y>=8: V.
// 8 waves = 4M x 2N of 64x64; per k-iter 128 MFMA per 24KB staged (vs 64
// per 16KB at 128^2) — +33% intensity, 3 DMA/thread (vs 4), 48KB LDS ->
// 3 blocks/CU = 6 waves/SIMD. T4 counted-vmcnt(3) pipeline.
__global__ __launch_bounds__(512) void gemm_qkv(const __hip_bfloat16* __restrict__ A,
                                                const __hip_bfloat16* __restrict__ Bw,
                                                __hip_bfloat16* __restrict__ Qw,
                                                __hip_bfloat16* __restrict__ Kw,
                                                __hip_bfloat16* __restrict__ Vtw) {
    __shared__ union {
        struct { __hip_bfloat16 As[2][256 * 32]; __hip_bfloat16 Bs[2][128 * 32]; } s;  // 48KB
        __hip_bfloat16 T[64 * 264];   // 33.8KB epilogue (QK: stride 138; V: 264)
    } u;
    const int tid = threadIdx.x;
    const int wave = tid >> 6, lane = tid & 63;
    const int m0 = blockIdx.x * 256, n0 = blockIdx.y * 128;

    const bool isQ = (blockIdx.y < 4);
    if (isQ && (m0 & 2047) >= 1024) return;   // Q of c-rows: output discarded

    const int la = lane >> 2;
    const int kc = (lane & 3) * 8;
    // A: rows wave*32 + [0,32); B: rows wave*16 + [0,16)
    const long ga0 = (long)(m0 + wave * 32 + la) * 512 + kc;
    const long ga1 = (long)(m0 + wave * 32 + 16 + la) * 512 + kc;
    const long gb0 = (long)(n0 + wave * 16 + la) * 512 + kc;

    f32x4 acc[4][4] = {};
    const int mw = (wave & 3) * 64, nw = (wave >> 2) * 64;
    const int lrow = lane & 15, lk = (lane >> 4) * 8;

    // prologue: stage k-tile 0 into buf 0 (3 DMA/thread in flight)
    gload_lds16(A + ga0, &u.s.As[0][wave * 1024]);
    gload_lds16(A + ga1, &u.s.As[0][wave * 1024 + 512]);
    gload_lds16(Bw + gb0, &u.s.Bs[0][wave * 512]);

    for (int it = 0; it < 16; ++it) {
        const int cur = it & 1;
        if (it < 15) {
            const int k0 = (it + 1) * 32;
            gload_lds16(A + ga0 + k0, &u.s.As[cur ^ 1][wave * 1024]);
            gload_lds16(A + ga1 + k0, &u.s.As[cur ^ 1][wave * 1024 + 512]);
            gload_lds16(Bw + gb0 + k0, &u.s.Bs[cur ^ 1][wave * 512]);
            WAITV3_BAR();   // tile `it` landed for all waves; tile it+1 flies
        } else {
            WAITV0_BAR();
        }
        v8bf a[4], b[4];
#pragma unroll
        for (int i = 0; i < 4; i++) {
            a[i] = *(const v8bf*)&u.s.As[cur][(mw + i * 16 + lrow) * 32 + lk];
            b[i] = *(const v8bf*)&u.s.Bs[cur][(nw + i * 16 + lrow) * 32 + lk];
        }
        __builtin_amdgcn_s_setprio(1);
#pragma unroll
        for (int mi = 0; mi < 4; mi++)
#pragma unroll
            for (int ni = 0; ni < 4; ni++)
                acc[mi][ni] = __builtin_amdgcn_mfma_f32_16x16x32_bf16(a[mi], b[ni], acc[mi][ni], 0, 0, 0);
        __builtin_amdgcn_s_setprio(0);
        RAW_BAR();   // all waves done reading buf[cur]; next DMA may overwrite
    }

    const int lq = lane >> 4;
    const int b_ = m0 >> 11;
    if (blockIdx.y < 8) {
        // ---- coalesced Q/K epilogue via T[64][138], 4 passes of 64 m-rows --
        const float qs = isQ ? 0.1803368801f : 1.f;   // 0.125*log2(e) folded into Q
#pragma unroll
        for (int pass = 0; pass < 4; ++pass) {
            if (pass) __syncthreads();             // prior pass's stores done
            if ((wave & 3) == pass) {              // 2 waves own m-slice pass*64
#pragma unroll
                for (int mi = 0; mi < 4; mi++)
#pragma unroll
                    for (int ni = 0; ni < 4; ni++) {
                        const int nl = nw + ni * 16 + lrow;
#pragma unroll
                        for (int r = 0; r < 4; r++)
                            u.T[(mi * 16 + lq * 4 + r) * 138 + nl] =
                                __float2bfloat16(acc[mi][ni][r] * qs);
                    }
            }
            __syncthreads();
#pragma unroll
            for (int i = 0; i < 2; i++) {
                int sI = tid + i * 512;            // 0..1023: 64 rows x 16 chunks
                int row = sI >> 4, ch = sI & 15;
                int grow = m0 + pass * 64 + row;
                int rr = grow & 2047;
                int gcol = n0 + ch * 8;
                int h = (gcol & 511) >> 6, dh = gcol & 63;
                uint4 v = *(const uint4*)&u.T[row * 138 + ch * 8];
                if (isQ)
                    *(uint4*)&Qw[((long)(b_ * 8 + h) * 1024 + rr) * 64 + dh] = v;
                else
                    *(uint4*)&Kw[((long)(b_ * 8 + h) * 2048 + rr) * 64 + dh] = v;
            }
        }
    } else {
        const int no = (blockIdx.y - 8) * 128;
        const int rrb = m0 & 2047;
#pragma unroll
        for (int pass = 0; pass < 2; ++pass) {
            __syncthreads();
            if ((wave >> 2) == pass) {             // 4 waves own n-slice pass*64
#pragma unroll
                for (int mi = 0; mi < 4; mi++)
#pragma unroll
                    for (int ni = 0; ni < 4; ni++) {
                        int n_l = ni * 16 + lrow;          // 0..63 within pass
                        int m_l = mw + mi * 16 + lq * 4;   // 0..255
                        ushort4 pk;
                        pk.x = f2bf(acc[mi][ni][0]); pk.y = f2bf(acc[mi][ni][1]);
                        pk.z = f2bf(acc[mi][ni][2]); pk.w = f2bf(acc[mi][ni][3]);
                        *(ushort4*)&u.T[n_l * 264 + m_l] = pk;
                    }
            }
            __syncthreads();
#pragma unroll
            for (int i = 0; i < 4; i++) {
                int sI = tid + i * 512;                    // 0..2047
                int n_l = sI >> 5, ch = sI & 31;           // 64 rows x 32 chunks
                int ng = no + pass * 64 + n_l;
                int h = ng >> 6, dh = ng & 63;
                uint4 v = *(const uint4*)&u.T[n_l * 264 + ch * 8];
                *(uint4*)&Vtw[((long)(b_ * 8 + h) * 64 + dh) * 2048 + rrb + ch * 8] = v;
            }
        }
    }
}

// ---- output projection GEMM: d_out[m,n] = sum_k Yb[m,k]*Wp[n,k], fp32 out
// v3: counted-vmcnt pipeline (T4).
__global__ __launch_bounds__(256) void gemm_out(const __hip_bfloat16* __restrict__ A,
                                                const __hip_bfloat16* __restrict__ Bw,
                                                float* __restrict__ outp) {
    __shared__ __hip_bfloat16 As[2][128 * 32];
    __shared__ __hip_bfloat16 Bs[2][128 * 32];
    const int tid = threadIdx.x;
    const int wave = tid >> 6, lane = tid & 63;
    const int m0 = blockIdx.x * 128, n0 = blockIdx.y * 128;

    const int la = lane >> 2;
    const int kc = (lane & 3) * 8;
    const long ga0 = (long)(m0 + wave * 16 + la) * 512 + kc;
    const long ga1 = (long)(m0 + (wave + 4) * 16 + la) * 512 + kc;
    const long gb0 = (long)(n0 + wave * 16 + la) * 512 + kc;
    const long gb1 = (long)(n0 + (wave + 4) * 16 + la) * 512 + kc;

    f32x4 acc[4][4] = {};
    const int mw = (wave & 1) * 64, nw = (wave >> 1) * 64;
    const int lrow = lane & 15, lk = (lane >> 4) * 8;

    gload_lds16(A + ga0, &As[0][wave * 512]);
    gload_lds16(A + ga1, &As[0][(wave + 4) * 512]);
    gload_lds16(Bw + gb0, &Bs[0][wave * 512]);
    gload_lds16(Bw + gb1, &Bs[0][(wave + 4) * 512]);

    for (int it = 0; it < 16; ++it) {
        const int cur = it & 1;
        if (it < 15) {
            const int k0 = (it + 1) * 32;
            gload_lds16(A + ga0 + k0, &As[cur ^ 1][wave * 512]);
            gload_lds16(A + ga1 + k0, &As[cur ^ 1][(wave + 4) * 512]);
            gload_lds16(Bw + gb0 + k0, &Bs[cur ^ 1][wave * 512]);
            gload_lds16(Bw + gb1 + k0, &Bs[cur ^ 1][(wave + 4) * 512]);
            WAITV4_BAR();
        } else {
            WAITV0_BAR();
        }
        v8bf a[4], b[4];
#pragma unroll
        for (int i = 0; i < 4; i++) {
            a[i] = *(const v8bf*)&As[cur][(mw + i * 16 + lrow) * 32 + lk];
            b[i] = *(const v8bf*)&Bs[cur][(nw + i * 16 + lrow) * 32 + lk];
        }
        __builtin_amdgcn_s_setprio(1);
#pragma unroll
        for (int mi = 0; mi < 4; mi++)
#pragma unroll
            for (int ni = 0; ni < 4; ni++)
                acc[mi][ni] = __builtin_amdgcn_mfma_f32_16x16x32_bf16(a[mi], b[ni], acc[mi][ni], 0, 0, 0);
        __builtin_amdgcn_s_setprio(0);
        RAW_BAR();
    }

    const int lq = lane >> 4;
#pragma unroll
    for (int mi = 0; mi < 4; mi++)
#pragma unroll
        for (int ni = 0; ni < 4; ni++)
#pragma unroll
            for (int r = 0; r < 4; r++) {
                int grow = m0 + mw + mi * 16 + lq * 4 + r;
                int gcol = n0 + nw + ni * 16 + lrow;
                outp[(long)grow * 512 + gcol] = acc[mi][ni][r];
            }
}

// ---- flash attention v14 (reverted known-good): 512-thread blocks --------
// grid 512 (b=L&7 XCD-pinned, qt2=(L>>3)&7, h=L>>6). 8 waves covering 128 q
// rows (wave w owns rows qt2*128+w*16); ONE K/V staging pipeline shared by
// all 8 waves: each thread stages 1 K uint4 + 1 V uint4 per tile. dbuf LDS,
// ONE __syncthreads per tile. Softmax = v13 (keep-bits, v_bfe_i32, pk_add).
// (v15/v16 permuted-V b128 PV: failed then regressed (+2us, conflicts 2x) —
// 16x ds_read_b64 with LDT=72 padding is the best verified V path.)
__global__ __launch_bounds__(512) void flash(const __hip_bfloat16* __restrict__ Q,
                                             const __hip_bfloat16* __restrict__ K,
                                             const __hip_bfloat16* __restrict__ Vt,
                                             const unsigned long long* __restrict__ Mbt,
                                             __hip_bfloat16* __restrict__ Y) {
    constexpr int LDT = 72;
    __shared__ __hip_bfloat16 Ks[2][64 * LDT];    // [buf][key][d]
    __shared__ __hip_bfloat16 Vts[2][64 * LDT];   // [buf][d][key]

    const int L = blockIdx.x;
    const int b = L & 7, qt2 = (L >> 3) & 7, h = L >> 6;
    const int bh = b * 8 + h;
    const int tid = threadIdx.x, w = tid >> 6, lane = tid & 63;
    const int lcol = lane & 15, lq = lane >> 4;
    const int qrow = qt2 * 128 + w * 16;          // wave's q-row base

    const __hip_bfloat16* Qp = Q + ((long)bh * 1024 + qrow + lcol) * 64 + lq * 8;
    const __hip_bfloat16* Kg = K + (long)bh * 2048 * 64;
    const __hip_bfloat16* Vg = Vt + (long)bh * 64 * 2048;
    const unsigned long long* Mp = Mbt + (long)b * 32 * 1024 + qrow + lcol;

    // staging geometry: ONE 16B chunk per thread per tile for K and for V
    const int r0 = tid >> 3, p0 = tid & 7;        // row 0..63, 16B part 0..7
    const __hip_bfloat16* Vp0 = Vg + (long)r0 * 2048 + p0 * 8;

    // per-lane mask-bit offsets (within 32-bit half): bit = (nt&1)*16+lq*4+j
    int boff[8];
#pragma unroll
    for (int jj = 0; jj < 8; jj++)
        boff[jj] = (jj >> 2) * 16 + lq * 4 + (jj & 3);

    // Q B-frags (wave's 16 q rows), pre-scaled by 0.125*log2e
    v8bf bq0 = *(const v8bf*)(Qp);
    v8bf bq1 = *(const v8bf*)(Qp + 32);

    f32x4 O[4] = {};
    f32x2 ls = {0.f, 0.f};

    // prologue: stage tile 0 into buf 0; preload keep word 0
    unsigned long long mword = Mp[0];
    {
        uint4 k0 = ((const uint4*)Kg)[tid];
        uint4 v0 = *(const uint4*)(Vp0);
        *(uint4*)&Ks[0][r0 * LDT + p0 * 8] = k0;
        *(uint4*)&Vts[0][r0 * LDT + p0 * 8] = v0;
    }
    __syncthreads();

    int cur = 0;
    for (int kt = 0; kt < 32; kt++) {
        // keep-bits, split into 32-bit halves (already inverted by cvt_mask)
        const unsigned int kw_lo = (unsigned int)mword;
        const unsigned int kw_hi = (unsigned int)(mword >> 32);

        // issue next tile's global loads NOW; latency hides under compute
        uint4 nk0, nv0;
        if (kt < 31) {
            nk0 = ((const uint4*)(Kg + ((kt + 1) << 12)))[tid];
            nv0 = *(const uint4*)(Vp0 + (kt + 1) * 64);
            mword = Mp[(long)(kt + 1) * 1024];
        }

        const __hip_bfloat16* Kb = Ks[cur];
        const __hip_bfloat16* Vb = Vts[cur];
#pragma unroll
        for (int nt = 0; nt < 4; nt++) {
            // S^T[key][q]: A = K rows (m=key=nt*16+lcol, k=d), B = Q
            v8bf ak0 = *(const v8bf*)&Kb[(nt * 16 + lcol) * LDT + lq * 8];
            v8bf ak1 = *(const v8bf*)&Kb[(nt * 16 + lcol) * LDT + 32 + lq * 8];
            f32x4 st = {};
            __builtin_amdgcn_s_setprio(1);
            st = __builtin_amdgcn_mfma_f32_16x16x32_bf16(ak0, bq0, st, 0, 0, 0);
            st = __builtin_amdgcn_mfma_f32_16x16x32_bf16(ak1, bq1, st, 0, 0, 0);
            __builtin_amdgcn_s_setprio(0);
            // keep-bit (sign-extended via v_bfe_i32) AND on exp2 bits
            const unsigned int kw = (nt < 2) ? kw_lo : kw_hi;
            const int base = (nt & 1) * 4;
            float e0 = andf(__builtin_amdgcn_exp2f(st[0]), sbit(kw, boff[base + 0]));
            float e1 = andf(__builtin_amdgcn_exp2f(st[1]), sbit(kw, boff[base + 1]));
            float e2 = andf(__builtin_amdgcn_exp2f(st[2]), sbit(kw, boff[base + 2]));
            float e3 = andf(__builtin_amdgcn_exp2f(st[3]), sbit(kw, boff[base + 3]));
            ls += (f32x2){e0, e1} + (f32x2){e2, e3};   // packed adds
            // pack P: element j = key nt*16+lq*4+j — already K=16 A-layout
            __hip_bfloat162 lo = __float22bfloat162_rn(make_float2(e0, e1));
            __hip_bfloat162 hi = __float22bfloat162_rn(make_float2(e2, e3));
            uint2 pku;
            __builtin_memcpy(&pku.x, &lo, 4);
            __builtin_memcpy(&pku.y, &hi, 4);
            v4s pa = __builtin_bit_cast(v4s, pku);
            // PV: O[q][d] += P[q][key16] * V[key16][d]; B-frags from Vts
            __builtin_amdgcn_s_setprio(1);
#pragma unroll
            for (int nd = 0; nd < 4; nd++) {
                v4s bv = *(const v4s*)&Vb[(nd * 16 + lcol) * LDT + nt * 16 + lq * 4];
                O[nd] = mfma16x16x16bf(pa, bv, O[nd]);
            }
            __builtin_amdgcn_s_setprio(0);
        }

        // write next tile into the other buffer; all waves finished reading
        // it before the previous barrier
        if (kt < 31) {
            *(uint4*)&Ks[cur ^ 1][r0 * LDT + p0 * 8] = nk0;
            *(uint4*)&Vts[cur ^ 1][r0 * LDT + p0 * 8] = nv0;
        }
        __syncthreads();
        cur ^= 1;
    }

    // row-sum: reduce over lq groups (lanes sharing lcol)
    float s = ls[0] + ls[1];
    s += __shfl_xor(s, 16);
    s += __shfl_xor(s, 32);
    // O C-layout rows are q = lq*4 + r; fetch matching 1/sum via shuffle
    float inv[4];
#pragma unroll
    for (int r = 0; r < 4; r++) inv[r] = 1.f / __shfl(s, lq * 4 + r);

    __hip_bfloat16* Yp = Y + ((long)b * 1024 + qrow) * 512 + h * 64 + lcol;
#pragma unroll
    for (int nd = 0; nd < 4; nd++)
#pragma unroll
        for (int r = 0; r < 4; r++)
            Yp[(long)(lq * 4 + r) * 512 + nd * 16] = __float2bfloat16(O[nd][r] * inv[r]);
}

// ---- launch -------------------------------------------------------------
extern "C" void kernel_launch(void* const* d_in, const int* in_sizes, int n_in,
                              void* d_out, int out_size, void* d_ws, size_t ws_size,
                              hipStream_t stream) {
    const float* x = (const float*)d_in[0];
    const float* c = (const float*)d_in[1];
    const int* mask = (const int*)d_in[2];
    const float* Wq = (const float*)d_in[3];
    const float* Wk = (const float*)d_in[4];
    const float* Wv = (const float*)d_in[5];
    const float* Wp = (const float*)d_in[6];

    char* ws = (char*)d_ws;
    __hip_bfloat16* xc  = (__hip_bfloat16*)(ws);                 // 16 MB (dead after gemm_qkv)
    __hip_bfloat16* Wbf = (__hip_bfloat16*)(ws + 16777216);      //  2 MB
    __hip_bfloat16* Qw  = (__hip_bfloat16*)(ws + 18874368);      //  8 MB
    __hip_bfloat16* Kw  = (__hip_bfloat16*)(ws + 27262976);      // 16 MB
    __hip_bfloat16* Vtw = (__hip_bfloat16*)(ws + 44040192);      // 16 MB
    __hip_bfloat16* Yb  = (__hip_bfloat16*)(ws + 60817408);      //  8 MB
    unsigned long long* Mbp = (unsigned long long*)(ws);         //  2 MB, aliases dead xc

    cvt_xcw<<<9216, 256, 0, stream>>>(x, c, Wq, Wk, Wv, Wp, xc, Wbf);
    gemm_qkv<<<dim3(64, 12), 512, 0, stream>>>(xc, Wbf, Qw, Kw, Vtw);
    cvt_mask<<<16384, 256, 0, stream>>>(mask, Mbp);   // after gemm_qkv: overwrites xc
    flash<<<512, 512, 0, stream>>>(Qw, Kw, Vtw, Mbp, Yb);
    gemm_out<<<dim3(64, 4), 256, 0, stream>>>(Yb, Wbf + 3 * 262144, (float*)d_out);
}

// Round 12
// 242.982 us; speedup vs baseline: 1.0596x; 1.0542x over previous
//
#include <hip/hip_runtime.h>
#include <hip/hip_bf16.h>
#include <stdint.h>

typedef __bf16 v8bf __attribute__((ext_vector_type(8)));
typedef short v4s __attribute__((ext_vector_type(4)));
typedef float f32x4 __attribute__((ext_vector_type(4)));
typedef float f32x2 __attribute__((ext_vector_type(2)));

__device__ __forceinline__ void gload_lds16(const void* g, void* l) {
    __builtin_amdgcn_global_load_lds(
        (const __attribute__((address_space(1))) void*)g,
        (__attribute__((address_space(3))) void*)l, 16, 0, 0);
}

__device__ __forceinline__ unsigned short f2bf(float f) {
    __hip_bfloat16 h = __float2bfloat16(f);
    return __builtin_bit_cast(unsigned short, h);
}

// zero e unless keep-bit (sign-extended to m) is set: e & m
__device__ __forceinline__ float andf(float e, int m) {
    return __builtin_bit_cast(float, __builtin_bit_cast(unsigned int, e) & (unsigned int)m);
}

// sign-extended single-bit extract: 1 VALU op (v_bfe_i32).
__device__ __forceinline__ int sbit(unsigned int w, int off) {
    int m;
    asm("v_bfe_i32 %0, %1, %2, 1" : "=v"(m) : "v"(w), "v"(off));
    return m;
}

// counted-vmcnt barriers (T4): raw s_barrier, loads stay in flight across it.
#define WAITV4_BAR() asm volatile("s_waitcnt vmcnt(4)\n\ts_barrier" ::: "memory")
#define WAITV0_BAR() asm volatile("s_waitcnt vmcnt(0)\n\ts_barrier" ::: "memory")
#define RAW_BAR() asm volatile("s_barrier" ::: "memory")

// K=16 bf16 MFMA: D = A*B + C. A,B = 4 bf16 (2 VGPRs).
// A layout: A[m=lane&15][k=(lane>>4)*4 + j]  == C/D layout of a prior MFMA.
__device__ __forceinline__ f32x4 mfma16x16x16bf(v4s a, v4s b, f32x4 c) {
#if __has_builtin(__builtin_amdgcn_mfma_f32_16x16x16bf16_1k)
    return __builtin_amdgcn_mfma_f32_16x16x16bf16_1k(a, b, c, 0, 0, 0);
#elif __has_builtin(__builtin_amdgcn_mfma_f32_16x16x16_bf16)
    return __builtin_amdgcn_mfma_f32_16x16x16_bf16(a, b, c, 0, 0, 0);
#else
    asm("s_nop 1\n\t"
        "v_mfma_f32_16x16x16_bf16 %0, %1, %2, %0\n\t"
        "s_nop 7\n\ts_nop 3"
        : "+v"(c) : "v"(a), "v"(b));
    return c;
#endif
}

// ---- fused conversion: xc = concat(x,c) bf16 [8][2048][512]; Wbf = 4 weights
__global__ __launch_bounds__(256) void cvt_xcw(const float* __restrict__ x,
                                               const float* __restrict__ c,
                                               const float* __restrict__ wq,
                                               const float* __restrict__ wk,
                                               const float* __restrict__ wv,
                                               const float* __restrict__ wp,
                                               __hip_bfloat16* __restrict__ xc,
                                               __hip_bfloat16* __restrict__ wout) {
    int bid = blockIdx.x;
    if (bid < 8192) {
        int i = bid * 256 + threadIdx.x;
        long e = (long)i * 4;
        int b = (int)(e >> 20);
        int rem = (int)(e & ((1 << 20) - 1));
        int r = rem >> 9;
        int col = rem & 511;
        const float* src = (r < 1024) ? (x + ((long)b << 19) + (long)r * 512 + col)
                                      : (c + ((long)b << 19) + (long)(r - 1024) * 512 + col);
        float4 v = *(const float4*)src;
        ushort4 o;
        o.x = f2bf(v.x); o.y = f2bf(v.y); o.z = f2bf(v.z); o.w = f2bf(v.w);
        ((ushort4*)xc)[i] = o;
    } else {
        int i = (bid - 8192) * 256 + threadIdx.x;
        int e = i * 4;
        int w = e >> 18;
        int off = e & ((1 << 18) - 1);
        const float* src = (w == 0 ? wq : w == 1 ? wk : w == 2 ? wv : wp) + off;
        float4 val = *(const float4*)src;
        ushort4 o;
        o.x = f2bf(val.x); o.y = f2bf(val.y); o.z = f2bf(val.z); o.w = f2bf(val.w);
        ((ushort4*)wout)[i] = o;
    }
}

// mask int32 [8][1024][2048] -> bit-packed KEEP-bits (inverted mask),
// TRANSPOSED uint64 [8][word 32][q 1024].
// v2: one thread per OUTPUT word — 16x int4 loads (16B/lane, coalescing
// sweet spot vs old 4B/lane), 64-bit local pack (no ballot), one coalesced
// 8B store per lane (vs old 1-lane-per-wave stores). Memory-bound floor
// ~11us for the 67MB mask read.
__global__ __launch_bounds__(256) void cvt_mask(const int* __restrict__ mask,
                                                unsigned long long* __restrict__ mbt) {
    const int bid = blockIdx.x, t = threadIdx.x;
    const int b = bid >> 7;            // 8 batches
    const int word = (bid >> 2) & 31;  // 32 key-words
    const int q = (bid & 3) * 256 + t; // 1024 q rows
    const int* src = mask + ((long)(b * 1024 + q) << 11) + word * 64;

    unsigned int lo = 0, hi = 0;
#pragma unroll
    for (int ii = 0; ii < 8; ii++) {
        int4 v = *(const int4*)(src + ii * 4);
        lo |= (unsigned int)(v.x == 0) << (ii * 4 + 0);
        lo |= (unsigned int)(v.y == 0) << (ii * 4 + 1);
        lo |= (unsigned int)(v.z == 0) << (ii * 4 + 2);
        lo |= (unsigned int)(v.w == 0) << (ii * 4 + 3);
    }
#pragma unroll
    for (int ii = 0; ii < 8; ii++) {
        int4 v = *(const int4*)(src + 32 + ii * 4);
        hi |= (unsigned int)(v.x == 0) << (ii * 4 + 0);
        hi |= (unsigned int)(v.y == 0) << (ii * 4 + 1);
        hi |= (unsigned int)(v.z == 0) << (ii * 4 + 2);
        hi |= (unsigned int)(v.w == 0) << (ii * 4 + 3);
    }
    uint2 o; o.x = lo; o.y = hi;       // uint64 LE: low word = keys 0..31
    ((uint2*)mbt)[(b * 32 + word) * 1024 + q] = o;
}

// ---- fused QKV projection GEMM ------------------------------------------
// C[m,n] = sum_k xc[m,k]*Wbf[n,k], M=16384, N=1536. y<4: Q (only x-rows,
// early-exit for c-row blocks), 4<=y<8: K, y>=8: V (2-pass LDS transpose).
// T4 counted-vmcnt main loop; coalesced Q/K epilogue via LDS T.
// (256x128/8-wave variant tried R11: +3.6us — 128^2 is the local optimum.)
__global__ __launch_bounds__(256) void gemm_qkv(const __hip_bfloat16* __restrict__ A,
                                                const __hip_bfloat16* __restrict__ Bw,
                                                __hip_bfloat16* __restrict__ Qw,
                                                __hip_bfloat16* __restrict__ Kw,
                                                __hip_bfloat16* __restrict__ Vtw) {
    __shared__ union {
        struct { __hip_bfloat16 As[2][128 * 32]; __hip_bfloat16 Bs[2][128 * 32]; } s;
        __hip_bfloat16 T[64 * 138];   // 17.6 KB epilogue buffer (QK: stride 138; V: 136)
    } u;
    const int tid = threadIdx.x;
    const int wave = tid >> 6, lane = tid & 63;
    const int m0 = blockIdx.x * 128, n0 = blockIdx.y * 128;

    const bool isQ = (blockIdx.y < 4);
    const int rr_base = m0 & 2047;
    if (isQ && rr_base >= 1024) return;   // Q of c-rows: output discarded

    const int la = lane >> 2;
    const int kc = (lane & 3) * 8;
    const long ga0 = (long)(m0 + wave * 16 + la) * 512 + kc;
    const long ga1 = (long)(m0 + (wave + 4) * 16 + la) * 512 + kc;
    const long gb0 = (long)(n0 + wave * 16 + la) * 512 + kc;
    const long gb1 = (long)(n0 + (wave + 4) * 16 + la) * 512 + kc;

    f32x4 acc[4][4] = {};
    const int mw = (wave & 1) * 64, nw = (wave >> 1) * 64;
    const int lrow = lane & 15, lk = (lane >> 4) * 8;

    // prologue: stage k-tile 0 into buf 0 (4 DMA in flight)
    gload_lds16(A + ga0, &u.s.As[0][wave * 512]);
    gload_lds16(A + ga1, &u.s.As[0][(wave + 4) * 512]);
    gload_lds16(Bw + gb0, &u.s.Bs[0][wave * 512]);
    gload_lds16(Bw + gb1, &u.s.Bs[0][(wave + 4) * 512]);

    for (int it = 0; it < 16; ++it) {
        const int cur = it & 1;
        if (it < 15) {
            const int k0 = (it + 1) * 32;
            gload_lds16(A + ga0 + k0, &u.s.As[cur ^ 1][wave * 512]);
            gload_lds16(A + ga1 + k0, &u.s.As[cur ^ 1][(wave + 4) * 512]);
            gload_lds16(Bw + gb0 + k0, &u.s.Bs[cur ^ 1][wave * 512]);
            gload_lds16(Bw + gb1 + k0, &u.s.Bs[cur ^ 1][(wave + 4) * 512]);
            WAITV4_BAR();   // tile `it` landed for all waves; tile it+1 flies
        } else {
            WAITV0_BAR();
        }
        v8bf a[4], b[4];
#pragma unroll
        for (int i = 0; i < 4; i++) {
            a[i] = *(const v8bf*)&u.s.As[cur][(mw + i * 16 + lrow) * 32 + lk];
            b[i] = *(const v8bf*)&u.s.Bs[cur][(nw + i * 16 + lrow) * 32 + lk];
        }
        __builtin_amdgcn_s_setprio(1);
#pragma unroll
        for (int mi = 0; mi < 4; mi++)
#pragma unroll
            for (int ni = 0; ni < 4; ni++)
                acc[mi][ni] = __builtin_amdgcn_mfma_f32_16x16x32_bf16(a[mi], b[ni], acc[mi][ni], 0, 0, 0);
        __builtin_amdgcn_s_setprio(0);
        RAW_BAR();   // all waves done reading buf[cur]; next DMA may overwrite
    }

    const int lq = lane >> 4;
    const int b_ = m0 >> 11;
    if (blockIdx.y < 8) {
        // ---- coalesced Q/K epilogue via T[64][138], 2 passes of 64 rows ----
        const float qs = isQ ? 0.1803368801f : 1.f;   // 0.125*log2(e) folded into Q
#pragma unroll
        for (int pass = 0; pass < 2; ++pass) {
            if (pass) __syncthreads();             // protect T reuse
            if ((wave & 1) == pass) {              // waves owning mw = pass*64
#pragma unroll
                for (int mi = 0; mi < 4; mi++)
#pragma unroll
                    for (int ni = 0; ni < 4; ni++) {
                        const int nl = nw + ni * 16 + lrow;
#pragma unroll
                        for (int r = 0; r < 4; r++)
                            u.T[(mi * 16 + lq * 4 + r) * 138 + nl] =
                                __float2bfloat16(acc[mi][ni][r] * qs);
                    }
            }
            __syncthreads();
#pragma unroll
            for (int i = 0; i < 4; i++) {
                int sI = tid + i * 256;            // 0..1023: 64 rows x 16 chunks
                int row = sI >> 4, ch = sI & 15;
                int grow = m0 + pass * 64 + row;
                int rr = grow & 2047;
                int gcol = n0 + ch * 8;
                int h = (gcol & 511) >> 6, dh = gcol & 63;
                uint4 v = *(const uint4*)&u.T[row * 138 + ch * 8];
                if (isQ)
                    *(uint4*)&Qw[((long)(b_ * 8 + h) * 1024 + rr) * 64 + dh] = v;
                else
                    *(uint4*)&Kw[((long)(b_ * 8 + h) * 2048 + rr) * 64 + dh] = v;
            }
        }
    } else {
        const int no = (blockIdx.y - 8) * 128;
        const int rrb = m0 & 2047;
#pragma unroll
        for (int pass = 0; pass < 2; ++pass) {
            __syncthreads();
            if ((wave >> 1) == pass) {
#pragma unroll
                for (int mi = 0; mi < 4; mi++)
#pragma unroll
                    for (int ni = 0; ni < 4; ni++) {
                        int n_l = ni * 16 + lrow;          // 0..63 within pass
                        int m_l = mw + mi * 16 + lq * 4;
                        ushort4 pk;
                        pk.x = f2bf(acc[mi][ni][0]); pk.y = f2bf(acc[mi][ni][1]);
                        pk.z = f2bf(acc[mi][ni][2]); pk.w = f2bf(acc[mi][ni][3]);
                        *(ushort4*)&u.T[n_l * 136 + m_l] = pk;
                    }
            }
            __syncthreads();
#pragma unroll
            for (int i = 0; i < 4; i++) {
                int sI = tid + i * 256;                    // 0..1023
                int n_l = sI >> 4, ch = sI & 15;           // 64 rows x 16 chunks
                int ng = no + pass * 64 + n_l;
                int h = ng >> 6, dh = ng & 63;
                uint4 v = *(const uint4*)&u.T[n_l * 136 + ch * 8];
                *(uint4*)&Vtw[((long)(b_ * 8 + h) * 64 + dh) * 2048 + rrb + ch * 8] = v;
            }
        }
    }
}

// ---- output projection GEMM: d_out[m,n] = sum_k Yb[m,k]*Wp[n,k], fp32 out
// v3: counted-vmcnt pipeline (T4).
__global__ __launch_bounds__(256) void gemm_out(const __hip_bfloat16* __restrict__ A,
                                                const __hip_bfloat16* __restrict__ Bw,
                                                float* __restrict__ outp) {
    __shared__ __hip_bfloat16 As[2][128 * 32];
    __shared__ __hip_bfloat16 Bs[2][128 * 32];
    const int tid = threadIdx.x;
    const int wave = tid >> 6, lane = tid & 63;
    const int m0 = blockIdx.x * 128, n0 = blockIdx.y * 128;

    const int la = lane >> 2;
    const int kc = (lane & 3) * 8;
    const long ga0 = (long)(m0 + wave * 16 + la) * 512 + kc;
    const long ga1 = (long)(m0 + (wave + 4) * 16 + la) * 512 + kc;
    const long gb0 = (long)(n0 + wave * 16 + la) * 512 + kc;
    const long gb1 = (long)(n0 + (wave + 4) * 16 + la) * 512 + kc;

    f32x4 acc[4][4] = {};
    const int mw = (wave & 1) * 64, nw = (wave >> 1) * 64;
    const int lrow = lane & 15, lk = (lane >> 4) * 8;

    gload_lds16(A + ga0, &As[0][wave * 512]);
    gload_lds16(A + ga1, &As[0][(wave + 4) * 512]);
    gload_lds16(Bw + gb0, &Bs[0][wave * 512]);
    gload_lds16(Bw + gb1, &Bs[0][(wave + 4) * 512]);

    for (int it = 0; it < 16; ++it) {
        const int cur = it & 1;
        if (it < 15) {
            const int k0 = (it + 1) * 32;
            gload_lds16(A + ga0 + k0, &As[cur ^ 1][wave * 512]);
            gload_lds16(A + ga1 + k0, &As[cur ^ 1][(wave + 4) * 512]);
            gload_lds16(Bw + gb0 + k0, &Bs[cur ^ 1][wave * 512]);
            gload_lds16(Bw + gb1 + k0, &Bs[cur ^ 1][(wave + 4) * 512]);
            WAITV4_BAR();
        } else {
            WAITV0_BAR();
        }
        v8bf a[4], b[4];
#pragma unroll
        for (int i = 0; i < 4; i++) {
            a[i] = *(const v8bf*)&As[cur][(mw + i * 16 + lrow) * 32 + lk];
            b[i] = *(const v8bf*)&Bs[cur][(nw + i * 16 + lrow) * 32 + lk];
        }
        __builtin_amdgcn_s_setprio(1);
#pragma unroll
        for (int mi = 0; mi < 4; mi++)
#pragma unroll
            for (int ni = 0; ni < 4; ni++)
                acc[mi][ni] = __builtin_amdgcn_mfma_f32_16x16x32_bf16(a[mi], b[ni], acc[mi][ni], 0, 0, 0);
        __builtin_amdgcn_s_setprio(0);
        RAW_BAR();
    }

    const int lq = lane >> 4;
#pragma unroll
    for (int mi = 0; mi < 4; mi++)
#pragma unroll
        for (int ni = 0; ni < 4; ni++)
#pragma unroll
            for (int r = 0; r < 4; r++) {
                int grow = m0 + mw + mi * 16 + lq * 4 + r;
                int gcol = n0 + nw + ni * 16 + lrow;
                outp[(long)grow * 512 + gcol] = acc[mi][ni][r];
            }
}

// ---- flash attention v14 (known-good): 512-thread blocks -----------------
// grid 512 (b=L&7 XCD-pinned, qt2=(L>>3)&7, h=L>>6). 8 waves covering 128 q
// rows (wave w owns rows qt2*128+w*16); ONE K/V staging pipeline shared by
// all 8 waves: each thread stages 1 K uint4 + 1 V uint4 per tile. dbuf LDS,
// ONE __syncthreads per tile. Softmax = v13 (keep-bits, v_bfe_i32, pk_add).
__global__ __launch_bounds__(512) void flash(const __hip_bfloat16* __restrict__ Q,
                                             const __hip_bfloat16* __restrict__ K,
                                             const __hip_bfloat16* __restrict__ Vt,
                                             const unsigned long long* __restrict__ Mbt,
                                             __hip_bfloat16* __restrict__ Y) {
    constexpr int LDT = 72;
    __shared__ __hip_bfloat16 Ks[2][64 * LDT];    // [buf][key][d]
    __shared__ __hip_bfloat16 Vts[2][64 * LDT];   // [buf][d][key]

    const int L = blockIdx.x;
    const int b = L & 7, qt2 = (L >> 3) & 7, h = L >> 6;
    const int bh = b * 8 + h;
    const int tid = threadIdx.x, w = tid >> 6, lane = tid & 63;
    const int lcol = lane & 15, lq = lane >> 4;
    const int qrow = qt2 * 128 + w * 16;          // wave's q-row base

    const __hip_bfloat16* Qp = Q + ((long)bh * 1024 + qrow + lcol) * 64 + lq * 8;
    const __hip_bfloat16* Kg = K + (long)bh * 2048 * 64;
    const __hip_bfloat16* Vg = Vt + (long)bh * 64 * 2048;
    const unsigned long long* Mp = Mbt + (long)b * 32 * 1024 + qrow + lcol;

    // staging geometry: ONE 16B chunk per thread per tile for K and for V
    const int r0 = tid >> 3, p0 = tid & 7;        // row 0..63, 16B part 0..7
    const __hip_bfloat16* Vp0 = Vg + (long)r0 * 2048 + p0 * 8;

    // per-lane mask-bit offsets (within 32-bit half): bit = (nt&1)*16+lq*4+j
    int boff[8];
#pragma unroll
    for (int jj = 0; jj < 8; jj++)
        boff[jj] = (jj >> 2) * 16 + lq * 4 + (jj & 3);

    // Q B-frags (wave's 16 q rows), pre-scaled by 0.125*log2e
    v8bf bq0 = *(const v8bf*)(Qp);
    v8bf bq1 = *(const v8bf*)(Qp + 32);

    f32x4 O[4] = {};
    f32x2 ls = {0.f, 0.f};

    // prologue: stage tile 0 into buf 0; preload keep word 0
    unsigned long long mword = Mp[0];
    {
        uint4 k0 = ((const uint4*)Kg)[tid];
        uint4 v0 = *(const uint4*)(Vp0);
        *(uint4*)&Ks[0][r0 * LDT + p0 * 8] = k0;
        *(uint4*)&Vts[0][r0 * LDT + p0 * 8] = v0;
    }
    __syncthreads();

    int cur = 0;
    for (int kt = 0; kt < 32; kt++) {
        // keep-bits, split into 32-bit halves (already inverted by cvt_mask)
        const unsigned int kw_lo = (unsigned int)mword;
        const unsigned int kw_hi = (unsigned int)(mword >> 32);

        // issue next tile's global loads NOW; latency hides under compute
        uint4 nk0, nv0;
        if (kt < 31) {
            nk0 = ((const uint4*)(Kg + ((kt + 1) << 12)))[tid];
            nv0 = *(const uint4*)(Vp0 + (kt + 1) * 64);
            mword = Mp[(long)(kt + 1) * 1024];
        }

        const __hip_bfloat16* Kb = Ks[cur];
        const __hip_bfloat16* Vb = Vts[cur];
#pragma unroll
        for (int nt = 0; nt < 4; nt++) {
            // S^T[key][q]: A = K rows (m=key=nt*16+lcol, k=d), B = Q
            v8bf ak0 = *(const v8bf*)&Kb[(nt * 16 + lcol) * LDT + lq * 8];
            v8bf ak1 = *(const v8bf*)&Kb[(nt * 16 + lcol) * LDT + 32 + lq * 8];
            f32x4 st = {};
            __builtin_amdgcn_s_setprio(1);
            st = __builtin_amdgcn_mfma_f32_16x16x32_bf16(ak0, bq0, st, 0, 0, 0);
            st = __builtin_amdgcn_mfma_f32_16x16x32_bf16(ak1, bq1, st, 0, 0, 0);
            __builtin_amdgcn_s_setprio(0);
            // keep-bit (sign-extended via v_bfe_i32) AND on exp2 bits
            const unsigned int kw = (nt < 2) ? kw_lo : kw_hi;
            const int base = (nt & 1) * 4;
            float e0 = andf(__builtin_amdgcn_exp2f(st[0]), sbit(kw, boff[base + 0]));
            float e1 = andf(__builtin_amdgcn_exp2f(st[1]), sbit(kw, boff[base + 1]));
            float e2 = andf(__builtin_amdgcn_exp2f(st[2]), sbit(kw, boff[base + 2]));
            float e3 = andf(__builtin_amdgcn_exp2f(st[3]), sbit(kw, boff[base + 3]));
            ls += (f32x2){e0, e1} + (f32x2){e2, e3};   // packed adds
            // pack P: element j = key nt*16+lq*4+j — already K=16 A-layout
            __hip_bfloat162 lo = __float22bfloat162_rn(make_float2(e0, e1));
            __hip_bfloat162 hi = __float22bfloat162_rn(make_float2(e2, e3));
            uint2 pku;
            __builtin_memcpy(&pku.x, &lo, 4);
            __builtin_memcpy(&pku.y, &hi, 4);
            v4s pa = __builtin_bit_cast(v4s, pku);
            // PV: O[q][d] += P[q][key16] * V[key16][d]; B-frags from Vts
            __builtin_amdgcn_s_setprio(1);
#pragma unroll
            for (int nd = 0; nd < 4; nd++) {
                v4s bv = *(const v4s*)&Vb[(nd * 16 + lcol) * LDT + nt * 16 + lq * 4];
                O[nd] = mfma16x16x16bf(pa, bv, O[nd]);
            }
            __builtin_amdgcn_s_setprio(0);
        }

        // write next tile into the other buffer; all waves finished reading
        // it before the previous barrier
        if (kt < 31) {
            *(uint4*)&Ks[cur ^ 1][r0 * LDT + p0 * 8] = nk0;
            *(uint4*)&Vts[cur ^ 1][r0 * LDT + p0 * 8] = nv0;
        }
        __syncthreads();
        cur ^= 1;
    }

    // row-sum: reduce over lq groups (lanes sharing lcol)
    float s = ls[0] + ls[1];
    s += __shfl_xor(s, 16);
    s += __shfl_xor(s, 32);
    // O C-layout rows are q = lq*4 + r; fetch matching 1/sum via shuffle
    float inv[4];
#pragma unroll
    for (int r = 0; r < 4; r++) inv[r] = 1.f / __shfl(s, lq * 4 + r);

    __hip_bfloat16* Yp = Y + ((long)b * 1024 + qrow) * 512 + h * 64 + lcol;
#pragma unroll
    for (int nd = 0; nd < 4; nd++)
#pragma unroll
        for (int r = 0; r < 4; r++)
            Yp[(long)(lq * 4 + r) * 512 + nd * 16] = __float2bfloat16(O[nd][r] * inv[r]);
}

// ---- launch -------------------------------------------------------------
extern "C" void kernel_launch(void* const* d_in, const int* in_sizes, int n_in,
                              void* d_out, int out_size, void* d_ws, size_t ws_size,
                              hipStream_t stream) {
    const float* x = (const float*)d_in[0];
    const float* c = (const float*)d_in[1];
    const int* mask = (const int*)d_in[2];
    const float* Wq = (const float*)d_in[3];
    const float* Wk = (const float*)d_in[4];
    const float* Wv = (const float*)d_in[5];
    const float* Wp = (const float*)d_in[6];

    char* ws = (char*)d_ws;
    __hip_bfloat16* xc  = (__hip_bfloat16*)(ws);                 // 16 MB (dead after gemm_qkv)
    __hip_bfloat16* Wbf = (__hip_bfloat16*)(ws + 16777216);      //  2 MB
    __hip_bfloat16* Qw  = (__hip_bfloat16*)(ws + 18874368);      //  8 MB
    __hip_bfloat16* Kw  = (__hip_bfloat16*)(ws + 27262976);      // 16 MB
    __hip_bfloat16* Vtw = (__hip_bfloat16*)(ws + 44040192);      // 16 MB
    __hip_bfloat16* Yb  = (__hip_bfloat16*)(ws + 60817408);      //  8 MB
    unsigned long long* Mbp = (unsigned long long*)(ws);         //  2 MB, aliases dead xc

    cvt_xcw<<<9216, 256, 0, stream>>>(x, c, Wq, Wk, Wv, Wp, xc, Wbf);
    gemm_qkv<<<dim3(128, 12), 256, 0, stream>>>(xc, Wbf, Qw, Kw, Vtw);
    cvt_mask<<<1024, 256, 0, stream>>>(mask, Mbp);   // after gemm_qkv: overwrites xc
    flash<<<512, 512, 0, stream>>>(Qw, Kw, Vtw, Mbp, Yb);
    gemm_out<<<dim3(64, 4), 256, 0, stream>>>(Yb, Wbf + 3 * 262144, (float*)d_out);
}